// Round 6
// baseline (2086.265 us; speedup 1.0000x reference)
//
#include <hip/hip_runtime.h>
#include <stdint.h>

// NpiLstm: T=512, B=128, H=1024, IN=64 (63 x-features + 1 feedback)
// Feedback folded into recurrent weights: W_hh' = W_hh + w_fb (x) W_lin.
// 256 persistent blocks; 8 independent groups of 32; group g = batch rows
// [16g,16g+16), block mb owns gate-cols [32mb,32mb+32).
// R6: weights pinned register-resident (asm), A-fragments loaded DIRECTLY
// global->register in MFMA layout (no LDS staging, no zs), per-wave partial
// producer wait (wave w polls only its ~8 producers), double-buffered pbuf
// -> single barrier per step. Exchange protocol unchanged (sc0 sc1, proven).

typedef short short8 __attribute__((ext_vector_type(8)));
typedef float float4v __attribute__((ext_vector_type(4)));
typedef int int4v __attribute__((ext_vector_type(4)));

#define KP 1152      // padded K: 63 x | 1 zero | 1024 h | 64 zero-pad

__device__ __forceinline__ unsigned short f2bf(float f) {
  unsigned int u = __float_as_uint(f);
  u += 0x7fffu + ((u >> 16) & 1u);   // RNE
  return (unsigned short)(u >> 16);
}
__device__ __forceinline__ float sigm(float x) { return 1.0f / (1.0f + __expf(-x)); }
__device__ __forceinline__ float tanh_f(float x) {
  float ax = fabsf(x);
  float e = __expf(-2.0f * ax);
  float r = (1.0f - e) / (1.0f + e);
  return x < 0.0f ? -r : r;
}

// ---- build W_cat [4096][1152] bf16 and biases b1/b2 [4096] f32 ----
__global__ void prep_w(const float* __restrict__ W_ih, const float* __restrict__ W_hh,
                       const float* __restrict__ W_lin, const float* __restrict__ b_ih,
                       const float* __restrict__ b_hh, const float* __restrict__ b_lin,
                       unsigned short* __restrict__ Wcat, float* __restrict__ b1,
                       float* __restrict__ b2) {
  int idx = blockIdx.x * 256 + threadIdx.x;
  if (idx < 4096 * KP) {
    int j = idx / KP;
    int k = idx - j * KP;
    float v = 0.0f;
    if (k < 63) v = W_ih[j * 64 + k];
    else if (k >= 64 && k < 1088) {
      int kk = k - 64;
      v = W_hh[j * 1024 + kk] + W_ih[j * 64 + 63] * W_lin[kk];
    }
    Wcat[idx] = f2bf(v);
  }
  if (idx < 4096) {
    float wfb = W_ih[idx * 64 + 63];
    float base = b_ih[idx] + b_hh[idx];
    b1[idx] = base + 1e-9f * wfb;      // step 1: feedback value is INIT_OUT
    b2[idx] = base + b_lin[0] * wfb;   // steps >=2: folded b_lin feedback
  }
}

// ---- x -> bf16, padded to 64 channels ----
__global__ void prep_x(const float* __restrict__ x, unsigned short* __restrict__ xbf) {
  int idx = blockIdx.x * 256 + threadIdx.x;   // < 512*128*64 exactly
  int c = idx & 63;
  int bi = idx >> 6;
  unsigned short v = 0;
  if (c < 63) v = f2bf(x[bi * 63 + c]);
  xbf[idx] = v;
}

// ---- zero h0 buffers + flags ----
__global__ void initk(unsigned int* __restrict__ Hz, int* __restrict__ flags) {
  int idx = blockIdx.x * 256 + threadIdx.x;   // 0..65535
  Hz[idx] = 0u;
  Hz[idx + 65536] = 0u;
  if (idx < 1024) flags[idx] = 0;
}

// ---- persistent recurrent kernel: 256 blocks (1/CU), 256 threads ----
// wave wv handles K-tiles kt in [9wv, 9wv+9): kt 0,1 = x; kt 2..33 = h-chunk
// (kt-2) produced by block (kt-2); kt 34,35 = zero pad.
__global__ __launch_bounds__(256, 1) void lstm_rec(
    const unsigned short* __restrict__ Wcat, const unsigned short* __restrict__ xbf,
    const float* __restrict__ b1, const float* __restrict__ b2,
    const float* __restrict__ Wlin, unsigned short* __restrict__ Hbuf,
    float* __restrict__ outp, int* __restrict__ flags) {
  const int tid = threadIdx.x;
  const int bid = blockIdx.x;
  const int g = bid & 7;
  const int mb = bid >> 3;
  const int wv = tid >> 6;
  const int ln = tid & 63;
  const int lr = ln & 15;             // MFMA fragment row/col within 16
  const int lq = ln >> 4;             // k-quarter
  const int rp = wv * 2 + (ln >> 5);  // pointwise row-pair index 0..7
  const int c = ln & 31;              // pointwise col 0..31

  __shared__ __align__(16) float pbuf[2][4][8][16][20];  // dbuf [wave][ntile][col][row+pad]

  // ---- load B fragments (folded weights) into registers, once; PIN them ----
  short8 bf[8][9];   // [ntile = gate*2 + colhalf][local ktile]
#pragma unroll
  for (int n = 0; n < 8; ++n) {
    const unsigned short* wrow =
        Wcat + (size_t)((n >> 1) * 1024 + mb * 32 + (n & 1) * 16 + lr) * KP;
#pragma unroll
    for (int j = 0; j < 9; ++j)
      bf[n][j] = *reinterpret_cast<const short8*>(wrow + (wv * 9 + j) * 32 + lq * 8);
  }
#pragma unroll
  for (int n = 0; n < 8; ++n)
#pragma unroll
    for (int j = 0; j < 9; ++j)
      asm volatile("" : "+v"(bf[n][j]));   // forbid rematerialization -> resident

  // ---- K-tile geometry for this wave ----
  const int kb = wv * 9;
  const int jlo = (kb < 2) ? 2 : 0;          // first h-tile local index
  const int jhi = (kb + 9 > 34) ? 7 : 9;     // one past last h-tile local index
  const int pmin = (kb < 2) ? 0 : kb - 2;    // producer range
  const int pmax = (kb + 6 < 31) ? kb + 6 : 31;
  const int cnt = 4 * (pmax - pmin + 1);     // flags to check (<= 36)
  const int* fp = flags + g * 128 + 4 * pmin + ((ln < cnt) ? ln : cnt - 1);

  int hoff[9];   // per-tile byte offset into H slice (frag layout)
#pragma unroll
  for (int j = 0; j < 9; ++j)
    hoff[j] = ((g * 16 + lr) * 1024 + (kb + j - 2) * 32 + lq * 8) * 2;

  const int gcb = mb * 32 + c;     // this thread's gate/h column
  float bias2[4];
#pragma unroll
  for (int q = 0; q < 4; ++q) bias2[q] = b2[q * 1024 + gcb];
  const float wl = Wlin[gcb];
  float cs0 = 0.f, cs1 = 0.f;      // cell state (rows 2rp, 2rp+1) in registers

  for (int t = 1; t < 512; ++t) {
    const int tm1 = t - 1;
    // --- x prefetch (no dependency on flags; only wave 0 consumes) ---
    short8 xa0, xa1;
    if (kb == 0) {
      const unsigned short* xrow =
          xbf + (size_t)t * 8192 + (g * 16 + lr) * 64 + lq * 8;
      xa0 = *reinterpret_cast<const short8*>(xrow);
      xa1 = *reinterpret_cast<const short8*>(xrow + 32);
    }

    // --- partial wait: poll only THIS wave's producers ---
    if (t > 1) {
      int guard = 0;
      for (;;) {
        int v;
        asm volatile("global_load_dword %0, %1, off sc0 sc1\n\ts_waitcnt vmcnt(0)"
                     : "=v"(v) : "v"(fp) : "memory");
        if (__all(v >= tm1)) break;
        if (++guard > (1 << 18)) break;   // hang-safety valve
      }
    }

    // --- A-fragments: direct global->register in MFMA layout ---
    const unsigned short* hb = Hbuf + ((t - 1) & 1) * 131072;
    short8 af[9];
    if (kb == 0) { af[0] = xa0; af[1] = xa1; }
    if (jhi == 7) {
      short8 z8 = {0, 0, 0, 0, 0, 0, 0, 0};
      af[7] = z8; af[8] = z8;
    }
#pragma unroll
    for (int j = 0; j < 9; ++j)
      if (j >= jlo && j < jhi)
        asm volatile("global_load_dwordx4 %0, %1, %2 sc0 sc1"
                     : "=v"(af[j]) : "v"(hoff[j]), "s"(hb));
    asm volatile("s_waitcnt vmcnt(0)" ::: "memory");
    __builtin_amdgcn_sched_barrier(0);

    // --- MFMA: 8 N-tiles x 9 K-tiles (K-split across waves) ---
    float4v acc[8];
#pragma unroll
    for (int n = 0; n < 8; ++n) acc[n] = (float4v){0.f, 0.f, 0.f, 0.f};
#pragma unroll
    for (int j = 0; j < 9; ++j)
#pragma unroll
      for (int n = 0; n < 8; ++n)
        acc[n] = __builtin_amdgcn_mfma_f32_16x16x32_bf16(af[j], bf[n][j], acc[n], 0, 0, 0);

    // --- partials to LDS (dbuf) ---
#pragma unroll
    for (int n = 0; n < 8; ++n)
      *reinterpret_cast<float4v*>(&pbuf[t & 1][wv][n][lr][lq * 4]) = acc[n];
    __syncthreads();   // the ONLY barrier per step

    // --- pointwise: reduce 4 wave-partials, gates -> c,h (2 rows/thread) ---
    float ga0[4], ga1[4];
    const int nlo = c >> 4;
    const int cc = c & 15;
#pragma unroll
    for (int q = 0; q < 4; ++q) {
      float s0 = 0.f, s1 = 0.f;
#pragma unroll
      for (int w2 = 0; w2 < 4; ++w2) {
        const float* pp = &pbuf[t & 1][w2][q * 2 + nlo][cc][2 * rp];
        s0 += pp[0];
        s1 += pp[1];
      }
      ga0[q] = s0;
      ga1[q] = s1;
    }
    float lb0 = bias2[0], lb1 = bias2[1], lb2 = bias2[2], lb3 = bias2[3];
    if (t == 1) {
      lb0 = b1[gcb];
      lb1 = b1[1024 + gcb];
      lb2 = b1[2048 + gcb];
      lb3 = b1[3072 + gcb];
    }
    float i0 = sigm(ga0[0] + lb0), f0 = sigm(ga0[1] + lb1);
    float G0 = tanh_f(ga0[2] + lb2), o0 = sigm(ga0[3] + lb3);
    float i1 = sigm(ga1[0] + lb0), f1 = sigm(ga1[1] + lb1);
    float G1 = tanh_f(ga1[2] + lb2), o1 = sigm(ga1[3] + lb3);
    cs0 = f0 * cs0 + i0 * G0;
    cs1 = f1 * cs1 + i1 * G1;
    float h0v = o0 * tanh_f(cs0);
    float h1v = o1 * tanh_f(cs1);

    // --- publish h (coherence point), drain, per-wave flag ---
    unsigned short* Hd = Hbuf + (t & 1) * 131072;
    const int r0 = g * 16 + rp * 2;
    unsigned short* p0 = Hd + (size_t)r0 * 1024 + gcb;
    unsigned short* p1 = p0 + 1024;
    int hb0 = (int)f2bf(h0v), hb1 = (int)f2bf(h1v);
    asm volatile("global_store_short %0, %1, off sc0 sc1" :: "v"(p0), "v"(hb0) : "memory");
    asm volatile("global_store_short %0, %1, off sc0 sc1" :: "v"(p1), "v"(hb1) : "memory");
    asm volatile("s_waitcnt vmcnt(0)" ::: "memory");
    if (ln == 0) {
      int* fp2 = flags + g * 128 + mb * 4 + wv;
      asm volatile("global_store_dword %0, %1, off sc0 sc1" :: "v"(fp2), "v"(t) : "memory");
    }

    // --- W_lin partial for this block's 32 cols (after flag; off-chain) ---
    float pa = h0v * wl, pb = h1v * wl;
    pa += __shfl_xor(pa, 1); pb += __shfl_xor(pb, 1);
    pa += __shfl_xor(pa, 2); pb += __shfl_xor(pb, 2);
    pa += __shfl_xor(pa, 4); pb += __shfl_xor(pb, 4);
    pa += __shfl_xor(pa, 8); pb += __shfl_xor(pb, 8);
    pa += __shfl_xor(pa, 16); pb += __shfl_xor(pb, 16);
    if (c == 0) {
      outp[(size_t)(t * 128 + r0) * 32 + mb] = pa;
      outp[(size_t)(t * 128 + r0 + 1) * 32 + mb] = pb;
    }
  }
}

// ---- out[t][b] = b_lin + sum_mb outp[t][b][mb]; rows t=0 -> INIT_OUT ----
__global__ void finalize(const float* __restrict__ outp, const float* __restrict__ b_lin,
                         float* __restrict__ out) {
  int tid = threadIdx.x;
  int ln = tid & 63;
  int wv = tid >> 6;
  int half = ln >> 5;
  int lane = ln & 31;
  int row = blockIdx.x * 8 + wv * 2 + half;   // < 65536
  float v = outp[(size_t)row * 32 + lane];
  v += __shfl_xor(v, 1);
  v += __shfl_xor(v, 2);
  v += __shfl_xor(v, 4);
  v += __shfl_xor(v, 8);
  v += __shfl_xor(v, 16);
  if (lane == 0) out[row] = (row < 128) ? 1e-9f : (v + b_lin[0]);
}

extern "C" void kernel_launch(void* const* d_in, const int* in_sizes, int n_in,
                              void* d_out, int out_size, void* d_ws, size_t ws_size,
                              hipStream_t stream) {
  const float* x = (const float*)d_in[0];
  const float* W_ih = (const float*)d_in[1];
  const float* W_hh = (const float*)d_in[2];
  const float* b_ih = (const float*)d_in[3];
  const float* b_hh = (const float*)d_in[4];
  const float* W_lin = (const float*)d_in[5];
  const float* b_lin = (const float*)d_in[6];
  float* out = (float*)d_out;

  char* ws = (char*)d_ws;
  const size_t WS_WCAT = 0;                  // 4096*1152*2   = 9437184
  const size_t WS_XBF  = 9437184;            // 512*128*64*2  = 8388608
  const size_t WS_B1   = 17825792;           // 16384
  const size_t WS_B2   = 17842176;           // 16384
  const size_t WS_H    = 17858560;           // 2*128*1024*2  = 524288
  const size_t WS_OUTP = 18382848;           // 512*128*32*4  = 8388608
  const size_t WS_FLAG = 26771456;           // 4096
  if (ws_size < WS_FLAG + 4096) return;      // insufficient scratch -> fail loudly

  unsigned short* Wcat = (unsigned short*)(ws + WS_WCAT);
  unsigned short* xbf = (unsigned short*)(ws + WS_XBF);
  float* b1 = (float*)(ws + WS_B1);
  float* b2 = (float*)(ws + WS_B2);
  unsigned short* Hbuf = (unsigned short*)(ws + WS_H);
  float* outp = (float*)(ws + WS_OUTP);
  int* flags = (int*)(ws + WS_FLAG);

  prep_w<<<18432, 256, 0, stream>>>(W_ih, W_hh, W_lin, b_ih, b_hh, b_lin, Wcat, b1, b2);
  prep_x<<<16384, 256, 0, stream>>>(x, xbf);
  initk<<<256, 256, 0, stream>>>((unsigned int*)Hbuf, flags);
  lstm_rec<<<256, 256, 0, stream>>>(Wcat, xbf, b1, b2, W_lin, Hbuf, outp, flags);
  finalize<<<8192, 256, 0, stream>>>(outp, b_lin, out);
}

// Round 7
// 2051.797 us; speedup vs baseline: 1.0168x; 1.0168x over previous
//
#include <hip/hip_runtime.h>
#include <stdint.h>

// NpiLstm: T=512, B=128, H=1024, IN=64 (63 x-features + 1 feedback)
// Feedback folded into recurrent weights: W_hh' = W_hh + w_fb (x) W_lin.
// 256 persistent blocks; 8 independent groups of 32; group g = batch rows
// [16g,16g+16), block mb owns gate-cols [32mb,32mb+32).
// R7: weights forced RESIDENT in the unified register file — 60 fragments
// pinned to AGPRs ("a" constraint, 240 regs) + 12 to VGPRs (48 regs).
// gfx950 MFMA reads B directly from AGPR. (R5/R6's "+v"-only pin failed:
// 288 frags > 256 arch VGPRs -> allocator sank the loads into the loop,
// streaming 288KB/block/step from L2/IC — the dominant serial cost.)

typedef short short8 __attribute__((ext_vector_type(8)));
typedef float float4v __attribute__((ext_vector_type(4)));
typedef int int4v __attribute__((ext_vector_type(4)));

#define KP 1152      // padded K: 63 x | 1 zero | 1024 h | 64 zero-pad

__device__ __forceinline__ unsigned short f2bf(float f) {
  unsigned int u = __float_as_uint(f);
  u += 0x7fffu + ((u >> 16) & 1u);   // RNE
  return (unsigned short)(u >> 16);
}
__device__ __forceinline__ float sigm(float x) { return 1.0f / (1.0f + __expf(-x)); }
__device__ __forceinline__ float tanh_f(float x) {
  float ax = fabsf(x);
  float e = __expf(-2.0f * ax);
  float r = (1.0f - e) / (1.0f + e);
  return x < 0.0f ? -r : r;
}

// ---- build W_cat [4096][1152] bf16 and biases b1/b2 [4096] f32 ----
__global__ void prep_w(const float* __restrict__ W_ih, const float* __restrict__ W_hh,
                       const float* __restrict__ W_lin, const float* __restrict__ b_ih,
                       const float* __restrict__ b_hh, const float* __restrict__ b_lin,
                       unsigned short* __restrict__ Wcat, float* __restrict__ b1,
                       float* __restrict__ b2) {
  int idx = blockIdx.x * 256 + threadIdx.x;
  if (idx < 4096 * KP) {
    int j = idx / KP;
    int k = idx - j * KP;
    float v = 0.0f;
    if (k < 63) v = W_ih[j * 64 + k];
    else if (k >= 64 && k < 1088) {
      int kk = k - 64;
      v = W_hh[j * 1024 + kk] + W_ih[j * 64 + 63] * W_lin[kk];
    }
    Wcat[idx] = f2bf(v);
  }
  if (idx < 4096) {
    float wfb = W_ih[idx * 64 + 63];
    float base = b_ih[idx] + b_hh[idx];
    b1[idx] = base + 1e-9f * wfb;      // step 1: feedback value is INIT_OUT
    b2[idx] = base + b_lin[0] * wfb;   // steps >=2: folded b_lin feedback
  }
}

// ---- x -> bf16, padded to 64 channels ----
__global__ void prep_x(const float* __restrict__ x, unsigned short* __restrict__ xbf) {
  int idx = blockIdx.x * 256 + threadIdx.x;   // < 512*128*64 exactly
  int c = idx & 63;
  int bi = idx >> 6;
  unsigned short v = 0;
  if (c < 63) v = f2bf(x[bi * 63 + c]);
  xbf[idx] = v;
}

// ---- zero h0 buffers + flags ----
__global__ void initk(unsigned int* __restrict__ Hz, int* __restrict__ flags) {
  int idx = blockIdx.x * 256 + threadIdx.x;   // 0..65535
  Hz[idx] = 0u;
  Hz[idx + 65536] = 0u;
  if (idx < 1024) flags[idx] = 0;
}

// ---- persistent recurrent kernel: 256 blocks (1/CU), 256 threads ----
// wave wv handles K-tiles kt in [9wv, 9wv+9): kt 0,1 = x; kt 2..33 = h-chunk
// (kt-2) produced by block (kt-2); kt 34,35 = zero pad.
__global__ __launch_bounds__(256, 1) void lstm_rec(
    const unsigned short* __restrict__ Wcat, const unsigned short* __restrict__ xbf,
    const float* __restrict__ b1, const float* __restrict__ b2,
    const float* __restrict__ Wlin, unsigned short* __restrict__ Hbuf,
    float* __restrict__ outp, int* __restrict__ flags) {
  const int tid = threadIdx.x;
  const int bid = blockIdx.x;
  const int g = bid & 7;
  const int mb = bid >> 3;
  const int wv = tid >> 6;
  const int ln = tid & 63;
  const int lr = ln & 15;             // MFMA fragment row/col within 16
  const int lq = ln >> 4;             // k-quarter
  const int rp = wv * 2 + (ln >> 5);  // pointwise row-pair index 0..7
  const int c = ln & 31;              // pointwise col 0..31

  __shared__ __align__(16) float pbuf[2][4][8][16][20];  // dbuf [wave][ntile][col][row+pad]

  // ---- load B fragments (folded weights); pin RESIDENT: 60 in AGPR, 12 in VGPR ----
  short8 bf[8][9];   // [ntile = gate*2 + colhalf][local ktile]
#pragma unroll
  for (int n = 0; n < 8; ++n) {
    const unsigned short* wrow =
        Wcat + (size_t)((n >> 1) * 1024 + mb * 32 + (n & 1) * 16 + lr) * KP;
#pragma unroll
    for (int j = 0; j < 9; ++j)
      bf[n][j] = *reinterpret_cast<const short8*>(wrow + (wv * 9 + j) * 32 + lq * 8);
  }
#pragma unroll
  for (int n = 0; n < 8; ++n)
#pragma unroll
    for (int j = 0; j < 9; ++j) {
      if (n * 9 + j < 60)
        asm volatile("" : "+a"(bf[n][j]));   // park in AGPRs (240 regs)
      else
        asm volatile("" : "+v"(bf[n][j]));   // remaining 48 regs in VGPRs
    }

  // ---- K-tile geometry for this wave ----
  const int kb = wv * 9;
  const int jlo = (kb < 2) ? 2 : 0;          // first h-tile local index
  const int jhi = (kb + 9 > 34) ? 7 : 9;     // one past last h-tile local index
  const int pmin = (kb < 2) ? 0 : kb - 2;    // producer range
  const int pmax = (kb + 6 < 31) ? kb + 6 : 31;
  const int cnt = 4 * (pmax - pmin + 1);     // flags to check (<= 36)
  const int* fp = flags + g * 128 + 4 * pmin + ((ln < cnt) ? ln : cnt - 1);

  int hoff[9];   // per-tile byte offset into H slice (frag layout)
#pragma unroll
  for (int j = 0; j < 9; ++j)
    hoff[j] = ((g * 16 + lr) * 1024 + (kb + j - 2) * 32 + lq * 8) * 2;

  const int gcb = mb * 32 + c;     // this thread's gate/h column
  float bias2[4];
#pragma unroll
  for (int q = 0; q < 4; ++q) bias2[q] = b2[q * 1024 + gcb];
  const float wl = Wlin[gcb];
  float cs0 = 0.f, cs1 = 0.f;      // cell state (rows 2rp, 2rp+1) in registers

  for (int t = 1; t < 512; ++t) {
    const int tm1 = t - 1;
    // --- x prefetch (no dependency on flags; only wave 0 consumes) ---
    short8 xa0, xa1;
    if (kb == 0) {
      const unsigned short* xrow =
          xbf + (size_t)t * 8192 + (g * 16 + lr) * 64 + lq * 8;
      xa0 = *reinterpret_cast<const short8*>(xrow);
      xa1 = *reinterpret_cast<const short8*>(xrow + 32);
    }

    // --- partial wait: poll only THIS wave's producers ---
    if (t > 1) {
      int guard = 0;
      for (;;) {
        int v;
        asm volatile("global_load_dword %0, %1, off sc0 sc1\n\ts_waitcnt vmcnt(0)"
                     : "=v"(v) : "v"(fp) : "memory");
        if (__all(v >= tm1)) break;
        if (++guard > (1 << 18)) break;   // hang-safety valve
      }
    }

    // --- A-fragments: direct global->register in MFMA layout ---
    const unsigned short* hb = Hbuf + ((t - 1) & 1) * 131072;
    short8 af[9];
    if (kb == 0) { af[0] = xa0; af[1] = xa1; }
    if (jhi == 7) {
      short8 z8 = {0, 0, 0, 0, 0, 0, 0, 0};
      af[7] = z8; af[8] = z8;
    }
#pragma unroll
    for (int j = 0; j < 9; ++j)
      if (j >= jlo && j < jhi)
        asm volatile("global_load_dwordx4 %0, %1, %2 sc0 sc1"
                     : "=v"(af[j]) : "v"(hoff[j]), "s"(hb));
    asm volatile("s_waitcnt vmcnt(0)" ::: "memory");
    __builtin_amdgcn_sched_barrier(0);

    // --- MFMA: 8 N-tiles x 9 K-tiles (K-split across waves) ---
    float4v acc[8];
#pragma unroll
    for (int n = 0; n < 8; ++n) acc[n] = (float4v){0.f, 0.f, 0.f, 0.f};
#pragma unroll
    for (int j = 0; j < 9; ++j)
#pragma unroll
      for (int n = 0; n < 8; ++n)
        acc[n] = __builtin_amdgcn_mfma_f32_16x16x32_bf16(af[j], bf[n][j], acc[n], 0, 0, 0);

    // --- partials to LDS (dbuf) ---
#pragma unroll
    for (int n = 0; n < 8; ++n)
      *reinterpret_cast<float4v*>(&pbuf[t & 1][wv][n][lr][lq * 4]) = acc[n];
    __syncthreads();   // the ONLY barrier per step

    // --- pointwise: reduce 4 wave-partials, gates -> c,h (2 rows/thread) ---
    float ga0[4], ga1[4];
    const int nlo = c >> 4;
    const int cc = c & 15;
#pragma unroll
    for (int q = 0; q < 4; ++q) {
      float s0 = 0.f, s1 = 0.f;
#pragma unroll
      for (int w2 = 0; w2 < 4; ++w2) {
        const float* pp = &pbuf[t & 1][w2][q * 2 + nlo][cc][2 * rp];
        s0 += pp[0];
        s1 += pp[1];
      }
      ga0[q] = s0;
      ga1[q] = s1;
    }
    float lb0 = bias2[0], lb1 = bias2[1], lb2 = bias2[2], lb3 = bias2[3];
    if (t == 1) {
      lb0 = b1[gcb];
      lb1 = b1[1024 + gcb];
      lb2 = b1[2048 + gcb];
      lb3 = b1[3072 + gcb];
    }
    float i0 = sigm(ga0[0] + lb0), f0 = sigm(ga0[1] + lb1);
    float G0 = tanh_f(ga0[2] + lb2), o0 = sigm(ga0[3] + lb3);
    float i1 = sigm(ga1[0] + lb0), f1 = sigm(ga1[1] + lb1);
    float G1 = tanh_f(ga1[2] + lb2), o1 = sigm(ga1[3] + lb3);
    cs0 = f0 * cs0 + i0 * G0;
    cs1 = f1 * cs1 + i1 * G1;
    float h0v = o0 * tanh_f(cs0);
    float h1v = o1 * tanh_f(cs1);

    // --- publish h (coherence point), drain, per-wave flag ---
    unsigned short* Hd = Hbuf + (t & 1) * 131072;
    const int r0 = g * 16 + rp * 2;
    unsigned short* p0 = Hd + (size_t)r0 * 1024 + gcb;
    unsigned short* p1 = p0 + 1024;
    int hb0 = (int)f2bf(h0v), hb1 = (int)f2bf(h1v);
    asm volatile("global_store_short %0, %1, off sc0 sc1" :: "v"(p0), "v"(hb0) : "memory");
    asm volatile("global_store_short %0, %1, off sc0 sc1" :: "v"(p1), "v"(hb1) : "memory");
    asm volatile("s_waitcnt vmcnt(0)" ::: "memory");
    if (ln == 0) {
      int* fp2 = flags + g * 128 + mb * 4 + wv;
      asm volatile("global_store_dword %0, %1, off sc0 sc1" :: "v"(fp2), "v"(t) : "memory");
    }

    // --- W_lin partial for this block's 32 cols (after flag; off-chain) ---
    float pa = h0v * wl, pb = h1v * wl;
    pa += __shfl_xor(pa, 1); pb += __shfl_xor(pb, 1);
    pa += __shfl_xor(pa, 2); pb += __shfl_xor(pb, 2);
    pa += __shfl_xor(pa, 4); pb += __shfl_xor(pb, 4);
    pa += __shfl_xor(pa, 8); pb += __shfl_xor(pb, 8);
    pa += __shfl_xor(pa, 16); pb += __shfl_xor(pb, 16);
    if (c == 0) {
      outp[(size_t)(t * 128 + r0) * 32 + mb] = pa;
      outp[(size_t)(t * 128 + r0 + 1) * 32 + mb] = pb;
    }
  }
}

// ---- out[t][b] = b_lin + sum_mb outp[t][b][mb]; rows t=0 -> INIT_OUT ----
__global__ void finalize(const float* __restrict__ outp, const float* __restrict__ b_lin,
                         float* __restrict__ out) {
  int tid = threadIdx.x;
  int ln = tid & 63;
  int wv = tid >> 6;
  int half = ln >> 5;
  int lane = ln & 31;
  int row = blockIdx.x * 8 + wv * 2 + half;   // < 65536
  float v = outp[(size_t)row * 32 + lane];
  v += __shfl_xor(v, 1);
  v += __shfl_xor(v, 2);
  v += __shfl_xor(v, 4);
  v += __shfl_xor(v, 8);
  v += __shfl_xor(v, 16);
  if (lane == 0) out[row] = (row < 128) ? 1e-9f : (v + b_lin[0]);
}

extern "C" void kernel_launch(void* const* d_in, const int* in_sizes, int n_in,
                              void* d_out, int out_size, void* d_ws, size_t ws_size,
                              hipStream_t stream) {
  const float* x = (const float*)d_in[0];
  const float* W_ih = (const float*)d_in[1];
  const float* W_hh = (const float*)d_in[2];
  const float* b_ih = (const float*)d_in[3];
  const float* b_hh = (const float*)d_in[4];
  const float* W_lin = (const float*)d_in[5];
  const float* b_lin = (const float*)d_in[6];
  float* out = (float*)d_out;

  char* ws = (char*)d_ws;
  const size_t WS_WCAT = 0;                  // 4096*1152*2   = 9437184
  const size_t WS_XBF  = 9437184;            // 512*128*64*2  = 8388608
  const size_t WS_B1   = 17825792;           // 16384
  const size_t WS_B2   = 17842176;           // 16384
  const size_t WS_H    = 17858560;           // 2*128*1024*2  = 524288
  const size_t WS_OUTP = 18382848;           // 512*128*32*4  = 8388608
  const size_t WS_FLAG = 26771456;           // 4096
  if (ws_size < WS_FLAG + 4096) return;      // insufficient scratch -> fail loudly

  unsigned short* Wcat = (unsigned short*)(ws + WS_WCAT);
  unsigned short* xbf = (unsigned short*)(ws + WS_XBF);
  float* b1 = (float*)(ws + WS_B1);
  float* b2 = (float*)(ws + WS_B2);
  unsigned short* Hbuf = (unsigned short*)(ws + WS_H);
  float* outp = (float*)(ws + WS_OUTP);
  int* flags = (int*)(ws + WS_FLAG);

  prep_w<<<18432, 256, 0, stream>>>(W_ih, W_hh, W_lin, b_ih, b_hh, b_lin, Wcat, b1, b2);
  prep_x<<<16384, 256, 0, stream>>>(x, xbf);
  initk<<<256, 256, 0, stream>>>((unsigned int*)Hbuf, flags);
  lstm_rec<<<256, 256, 0, stream>>>(Wcat, xbf, b1, b2, W_lin, Hbuf, outp, flags);
  finalize<<<8192, 256, 0, stream>>>(outp, b_lin, out);
}